// Round 10
// baseline (209.039 us; speedup 1.0000x reference)
//
#include <hip/hip_runtime.h>
#include <math.h>

#define Nn 2048

// ---------------- workspace layout (bytes) ----------------
#define OFF_IDX    ((size_t)0)                    // 16*2048*20*4 = 2.62 MB
#define OFF_P2MAX  (((size_t)4)  << 20)           // 16*2048*128*2 = 8.39 MB (bf16)
#define OFF_P2MIN  (((size_t)13) << 20)           // 8.39 MB (bf16)
#define OFF_PS2    (((size_t)22) << 20)           // 128*2048 float = 1 MB
#define OFF_PQ2    (((size_t)23) << 20)           // 1 MB
#define OFF_STATS  (((size_t)24) << 20)
#define OFF_MOM    (OFF_STATS + 0)                // 27 double
#define OFF_A2C2   (OFF_STATS + 8192)             // 256 float
#define OFF_S3SUM  (OFF_STATS + 12288)            // 1024 double
#define OFF_S3SQ   (OFF_STATS + 20480)            // 1024 double
#define OFF_P3MAX  (OFF_STATS + 28672)            // 16*1024 uint
#define OFF_P3MIN  (OFF_STATS + 94208)            // 16*1024 uint
#define OFF_DOTS1  (OFF_STATS + 274432)           // 16*512 float
#define OFF_DOTS2  (OFF_STATS + 307200)           // 16*256 float
#define OFF_W2BF   (OFF_STATS + 323584)           // 128*64 bf16 (q-major)
#define OFF_W3BF   (OFF_STATS + 339968)           // 1024*128 bf16 (q-major)
#define WS_NEEDED  (OFF_STATS + 602112)

typedef __attribute__((ext_vector_type(8))) short bf16x8;
typedef __attribute__((ext_vector_type(4))) float f32x4;

__device__ __forceinline__ unsigned fkey(float f){
  unsigned u = __float_as_uint(f);
  return u ^ ((unsigned)((int)u >> 31) | 0x80000000u);   // monotone float->uint
}
__device__ __forceinline__ float fdec(unsigned k){
  unsigned u = (k & 0x80000000u) ? (k & 0x7FFFFFFFu) : ~k;
  return __uint_as_float(u);
}
__device__ __forceinline__ short f2bf(float x){
  unsigned u = __float_as_uint(x);
  u += 0x7fffu + ((u >> 16) & 1u);                // RNE
  return (short)(u >> 16);
}
__device__ __forceinline__ float bf2f(short v){
  return __uint_as_float(((unsigned)(unsigned short)v) << 16);
}
__device__ __forceinline__ unsigned med3u(unsigned a, unsigned b, unsigned c){
  unsigned d;
  asm("v_med3_u32 %0, %1, %2, %3" : "=v"(d) : "v"(a), "v"(b), "v"(c));
  return d;
}
// branch-free insert of x into ascending sorted top-20 (uint keys)
__device__ __forceinline__ void insert20u(unsigned (&m)[20], unsigned x){
  #pragma unroll
  for (int t = 0; t < 19; t++) m[t] = med3u(m[t], m[t+1], x);
  m[19] = (x > m[19]) ? x : m[19];
}

// ---------------- K0: init accumulators + bf16 weight pre-cast ----------------
__global__ __launch_bounds__(256) void k_setup(char* __restrict__ ws,
      const float* __restrict__ W2, const float* __restrict__ W3,
      short* __restrict__ W2BF, short* __restrict__ W3BF){
  int i = blockIdx.x*256 + threadIdx.x;
  if (i < 7168) ((unsigned*)(ws + OFF_MOM))[i] = 0u;       // MOM..S3SQ
  if (i < 16384){
    ((unsigned*)(ws + OFF_P3MAX))[i] = 0u;
    ((unsigned*)(ws + OFF_P3MIN))[i] = 0xFFFFFFFFu;
  }
  if (i < 12288) ((float*)(ws + OFF_DOTS1))[i] = 0.f;      // DOTS1+DOTS2
  if (i < 16384){                      // W3: (q, k-chunk of 8)
    int q = i >> 4, k0 = (i & 15)*8;
    bf16x8 vv;
    #pragma unroll
    for (int j = 0; j < 8; j++) vv[j] = f2bf(W3[(size_t)(k0+j)*1024 + q]);
    *(bf16x8*)&W3BF[q*128 + k0] = vv;
  } else if (i < 17408){               // W2: (q, k-chunk of 8)
    int id2 = i - 16384;
    int q = id2 >> 3, k0 = (id2 & 7)*8;
    bf16x8 vv;
    #pragma unroll
    for (int j = 0; j < 8; j++) vv[j] = f2bf(W2[(k0+j)*128 + q]);
    *(bf16x8*)&W2BF[q*64 + k0] = vv;
  }
}

// ---------------- K1: KNN top-20 via index-packed uint keys ----------------
// grid (64,16), block 512. 16 lanes/query x 128 candidates. Ordering key:
// nd' = Q.P - 0.5|P|^2 (order-equivalent to negdist: constant shift + scale).
// pk = (fkey(nd') & ~0x7FF) | (2047-m) packs the index into the low 11 bits
// (ties -> lowest index). One scan, register-only 4-stage butterfly merge,
// indices decoded straight from registers; structurally no wild indices.
__global__ __launch_bounds__(512) void k_knn(const float* __restrict__ pc,
                                             int* __restrict__ idxg,
                                             double* __restrict__ MOM){
  __shared__ float4 pts[Nn];           // 32 KB; w = -0.5*|P|^2
  __shared__ float momS[27];
  const int tid = threadIdx.x;
  const int b = blockIdx.y;
  const int n0 = blockIdx.x*32;
  const float* pcb = pc + b*3*Nn;
  for (int i = tid; i < Nn; i += 512){
    float x = pcb[i], y = pcb[Nn+i], z = pcb[2*Nn+i];
    pts[i] = make_float4(x, y, z, -0.5f*(x*x + y*y + z*z));
  }
  if (tid < 27) momS[tid] = 0.f;
  __syncthreads();

  const int ql = tid >> 4, c = tid & 15;
  const int n = n0 + ql;
  const float4 Q = pts[n];

  unsigned v[20];
  #pragma unroll
  for (int t = 0; t < 20; t++) v[t] = 0u;
  #pragma unroll 1
  for (int i = 0; i < 128; i += 4){
    int m0 = (i+0)*16 + c, m1 = (i+1)*16 + c, m2 = (i+2)*16 + c, m3 = (i+3)*16 + c;
    float4 P0 = pts[m0];
    float4 P1 = pts[m1];
    float4 P2 = pts[m2];
    float4 P3 = pts[m3];
    float nd0 = fmaf(Q.x, P0.x, fmaf(Q.y, P0.y, fmaf(Q.z, P0.z, P0.w)));
    float nd1 = fmaf(Q.x, P1.x, fmaf(Q.y, P1.y, fmaf(Q.z, P1.z, P1.w)));
    float nd2 = fmaf(Q.x, P2.x, fmaf(Q.y, P2.y, fmaf(Q.z, P2.z, P2.w)));
    float nd3 = fmaf(Q.x, P3.x, fmaf(Q.y, P3.y, fmaf(Q.z, P3.z, P3.w)));
    insert20u(v, (fkey(nd0) & 0xFFFFF800u) | (unsigned)(2047 - m0));
    insert20u(v, (fkey(nd1) & 0xFFFFF800u) | (unsigned)(2047 - m1));
    insert20u(v, (fkey(nd2) & 0xFFFFF800u) | (unsigned)(2047 - m2));
    insert20u(v, (fkey(nd3) & 0xFFFFF800u) | (unsigned)(2047 - m3));
  }

  // butterfly merge across the 16 lanes of this query (top-20-of-union is
  // associative, commutative, idempotent -> hypercube allreduce is exact)
  #pragma unroll
  for (int stage = 8; stage >= 1; stage >>= 1){
    unsigned w[20];
    #pragma unroll
    for (int t = 0; t < 20; t++) w[t] = (unsigned)__shfl_xor((int)v[t], stage);
    #pragma unroll
    for (int t = 0; t < 20; t++) insert20u(v, w[t]);
  }

  // decode + write indices; accumulate moments from this lane's slots
  int* myidx = &idxg[((size_t)((b<<11) + n))*20];
  float s1[6] = {0,0,0,0,0,0};
  float s2[21] = {0,0,0,0,0,0,0,0,0,0,0,0,0,0,0,0,0,0,0,0,0};
  #pragma unroll
  for (int t = 0; t < 2; t++){
    int slot = c + t*16;
    if (slot < 20){
      int m = 2047 - (int)(v[slot] & 0x7FFu);
      myidx[slot] = m;
      float4 P = pts[m];
      float e[6] = {Q.x, Q.y, Q.z, P.x - Q.x, P.y - Q.y, P.z - Q.z};
      int u = 0;
      #pragma unroll
      for (int a = 0; a < 6; a++){
        s1[a] += e[a];
        #pragma unroll
        for (int bq = a; bq < 6; bq++){ s2[u] += e[a]*e[bq]; u++; }
      }
    }
  }
  #pragma unroll
  for (int a = 0; a < 6; a++)
    for (int off = 32; off > 0; off >>= 1) s1[a] += __shfl_xor(s1[a], off);
  #pragma unroll
  for (int u = 0; u < 21; u++)
    for (int off = 32; off > 0; off >>= 1) s2[u] += __shfl_xor(s2[u], off);
  if ((tid & 63) == 0){
    #pragma unroll
    for (int a = 0; a < 6; a++) atomicAdd(&momS[a], s1[a]);
    #pragma unroll
    for (int u = 0; u < 21; u++) atomicAdd(&momS[6+u], s2[u]);
  }
  __syncthreads();
  if (tid < 27) atomicAdd(&MOM[tid], (double)momS[tid]);
}

// ---------------- K4: conv1+bn1+relu+conv2 via MFMA; coef1 folded in ----------------
__global__ __launch_bounds__(256) void k_conv12(const float* __restrict__ pc,
      const int* __restrict__ idxg, const double* __restrict__ MOM,
      const float* __restrict__ W1, const float* __restrict__ g1,
      const float* __restrict__ b1, const short* __restrict__ W2BF,
      float* __restrict__ PS2, float* __restrict__ PQ2,
      short* __restrict__ P2MAX, short* __restrict__ P2MIN){
  __shared__ float es[6][512];         // 12 KB
  __shared__ short h1s[256*64];        // 32 KB (reused for both chunks)
  __shared__ float w1s[448];
  __shared__ float ssum[128], ssq[128];
  const int tid = threadIdx.x;
  const int b = blockIdx.y;
  const int n0 = blockIdx.x*16;
  const float* pcb = pc + b*3*Nn;

  if (tid < 64){
    const int o = tid;
    const double inv = 1.0/655360.0;
    double w[6]; double m = 0.0;
    #pragma unroll
    for (int cc = 0; cc < 6; cc++){ w[cc] = (double)W1[cc*64+o]; m += w[cc]*MOM[cc]*inv; }
    double e2 = 0.0; int u = 0;
    #pragma unroll
    for (int cc = 0; cc < 6; cc++){
      #pragma unroll
      for (int cp = cc; cp < 6; cp++){
        double mm = MOM[6+u]*inv; u++;
        e2 += (cc == cp) ? w[cc]*w[cc]*mm : 2.0*w[cc]*w[cp]*mm;
      }
    }
    double var = e2 - m*m;
    double a = (double)g1[o] / sqrt(var + 1e-5);
    #pragma unroll
    for (int cc = 0; cc < 6; cc++) w1s[cc*64+o] = (float)(a*w[cc]);
    w1s[384+o] = (float)((double)b1[o] - a*m);
  }

  for (int s = tid; s < 512; s += 256){
    int nl = s >> 5, kk = s & 31;
    int n = n0 + nl;
    int kke = (kk < 20) ? kk : 0;
    int m = idxg[((size_t)((b<<11)+n))*20 + kke] & 2047;
    float cx = pcb[n],  cy = pcb[Nn+n],  cz = pcb[2*Nn+n];
    float px = pcb[m],  py = pcb[Nn+m],  pz = pcb[2*Nn+m];
    es[0][s] = cx;    es[1][s] = cy;    es[2][s] = cz;
    es[3][s] = px-cx; es[4][s] = py-cy; es[5][s] = pz-cz;
  }
  __syncthreads();

  const int l = tid & 63, wv = tid >> 6;
  const int col = l & 15, kc = l >> 4;

  bf16x8 Bf[2][2];
  #pragma unroll
  for (int qt = 0; qt < 2; qt++){
    int q = wv*32 + qt*16 + col;
    #pragma unroll
    for (int ks = 0; ks < 2; ks++)
      Bf[qt][ks] = *(const bf16x8*)&W2BF[q*64 + ks*32 + kc*8];
  }

  float smacc[2] = {0.f, 0.f}, sqacc[2] = {0.f, 0.f};
  const bool t1real = (kc == 0);

  #pragma unroll 1
  for (int ch = 0; ch < 2; ch++){
    for (int i = tid; i < 2048; i += 256){
      int sl = i >> 3, oc = i & 7;
      int s = (ch << 8) + sl;
      bf16x8 hv;
      #pragma unroll
      for (int j = 0; j < 8; j++){
        int o = oc*8 + j;
        float acc = w1s[384 + o];
        #pragma unroll
        for (int cc = 0; cc < 6; cc++) acc = fmaf(w1s[cc*64 + o], es[cc][s], acc);
        hv[j] = f2bf(fmaxf(acc, 0.f));
      }
      *(bf16x8*)&h1s[sl*64 + ((oc ^ (sl & 7)) << 3)] = hv;
    }
    __syncthreads();

    #pragma unroll 1
    for (int g2 = 0; g2 < 8; g2++){
      const int g = ch*8 + g2;
      bf16x8 Af[2][2];
      #pragma unroll
      for (int t = 0; t < 2; t++){
        int rl = g2*32 + t*16 + col;
        #pragma unroll
        for (int ks = 0; ks < 2; ks++){
          int chunk = (ks*4 + kc) ^ (rl & 7);
          Af[t][ks] = *(const bf16x8*)&h1s[rl*64 + chunk*8];
        }
      }
      #pragma unroll
      for (int qt = 0; qt < 2; qt++){
        f32x4 a0 = {0.f,0.f,0.f,0.f}, a1 = {0.f,0.f,0.f,0.f};
        a0 = __builtin_amdgcn_mfma_f32_16x16x32_bf16(Af[0][0], Bf[qt][0], a0, 0,0,0);
        a0 = __builtin_amdgcn_mfma_f32_16x16x32_bf16(Af[0][1], Bf[qt][1], a0, 0,0,0);
        a1 = __builtin_amdgcn_mfma_f32_16x16x32_bf16(Af[1][0], Bf[qt][0], a1, 0,0,0);
        a1 = __builtin_amdgcn_mfma_f32_16x16x32_bf16(Af[1][1], Bf[qt][1], a1, 0,0,0);
        float mx = a0[0], mn = a0[0], sm = 0.f, sq = 0.f;
        #pragma unroll
        for (int r = 0; r < 4; r++){
          float v0 = a0[r], v1 = a1[r];
          mx = fmaxf(mx, fmaxf(v0, v1));
          mn = fminf(mn, fminf(v0, v1));
          sm += v0; sq += v0*v0;
        }
        if (t1real){
          #pragma unroll
          for (int r = 0; r < 4; r++){ float v1 = a1[r]; sm += v1; sq += v1*v1; }
        }
        smacc[qt] += sm; sqacc[qt] += sq;
        mx = fmaxf(mx, __shfl_xor(mx, 16)); mx = fmaxf(mx, __shfl_xor(mx, 32));
        mn = fminf(mn, __shfl_xor(mn, 16)); mn = fminf(mn, __shfl_xor(mn, 32));
        if (kc == 0){
          size_t base = ((size_t)(b*Nn + n0 + g))*128 + (size_t)(wv*32 + qt*16 + col);
          P2MAX[base] = f2bf(mx);
          P2MIN[base] = f2bf(mn);
        }
      }
    }
    __syncthreads();
  }

  #pragma unroll
  for (int qt = 0; qt < 2; qt++){
    smacc[qt] += __shfl_xor(smacc[qt], 16); smacc[qt] += __shfl_xor(smacc[qt], 32);
    sqacc[qt] += __shfl_xor(sqacc[qt], 16); sqacc[qt] += __shfl_xor(sqacc[qt], 32);
    if (kc == 0){
      ssum[wv*32 + qt*16 + col] = smacc[qt];
      ssq [wv*32 + qt*16 + col] = sqacc[qt];
    }
  }
  __syncthreads();
  if (tid < 128){
    int bid = b*128 + blockIdx.x;
    PS2[tid*2048 + bid] = ssum[tid];
    PQ2[tid*2048 + bid] = ssq[tid];
  }
}

// ---------------- K5: bn2 affine from partial buffers ----------------
__global__ __launch_bounds__(256) void k_coef2(const float* __restrict__ PS2,
        const float* __restrict__ PQ2, const float* __restrict__ g2,
        const float* __restrict__ b2, float* __restrict__ A2C2){
  __shared__ float sred[4], qred[4];
  const int p = blockIdx.x;
  const int tid = threadIdx.x;
  float s = 0.f, q = 0.f;
  for (int i = tid; i < 2048; i += 256){ s += PS2[p*2048 + i]; q += PQ2[p*2048 + i]; }
  #pragma unroll
  for (int off = 32; off > 0; off >>= 1){ s += __shfl_xor(s, off); q += __shfl_xor(q, off); }
  if ((tid & 63) == 0){ sred[tid >> 6] = s; qred[tid >> 6] = q; }
  __syncthreads();
  if (tid == 0){
    double sum = (double)sred[0] + sred[1] + sred[2] + sred[3];
    double sq  = (double)qred[0] + qred[1] + qred[2] + qred[3];
    double mean = sum * (1.0/655360.0);
    double var  = sq  * (1.0/655360.0) - mean*mean;
    double a = (double)g2[p] / sqrt(var + 1e-5);
    A2C2[p]     = (float)a;
    A2C2[128+p] = (float)((double)b2[p] - a*mean);
  }
}

// ---------------- K6: bn2+relu + conv3 via MFMA; bn3 stats + n-pool ----------------
__global__ __launch_bounds__(256) void k_conv3(const short* __restrict__ P2MAX,
      const short* __restrict__ P2MIN, const float* __restrict__ A2C2,
      const short* __restrict__ W3BF, double* __restrict__ S3SUM,
      double* __restrict__ S3SQ, unsigned* __restrict__ P3MAX,
      unsigned* __restrict__ P3MIN){
  __shared__ short As[128*128];
  __shared__ float a2[128], c2[128];
  const int tid = threadIdx.x;
  const int b = blockIdx.y;
  const int n0 = blockIdx.x*128;
  const int qh = blockIdx.z;
  if (tid < 128){ a2[tid] = A2C2[tid]; c2[tid] = A2C2[128+tid]; }
  __syncthreads();

  for (int idx = tid; idx < 2048; idx += 256){
    int s = idx >> 4, oc = idx & 15;
    size_t base = ((size_t)(b*Nn + n0 + s))*128 + (size_t)(oc*8);
    bf16x8 vmx = *(const bf16x8*)&P2MAX[base];
    bf16x8 vmn = *(const bf16x8*)&P2MIN[base];
    bf16x8 vv;
    #pragma unroll
    for (int j = 0; j < 8; j++){
      int o = oc*8 + j;
      float aa = a2[o];
      float vsel = bf2f((aa >= 0.f) ? vmx[j] : vmn[j]);
      vv[j] = f2bf(fmaxf(aa*vsel + c2[o], 0.f));
    }
    int chunk = oc ^ (s & 7);
    *(bf16x8*)&As[s*128 + chunk*8] = vv;
  }
  __syncthreads();

  const int l = tid & 63, wv = tid >> 6;
  const int col = l & 15, kc = l >> 4;

  #pragma unroll 1
  for (int pass = 0; pass < 2; ++pass){
    bf16x8 Bf[4][4];
    #pragma unroll
    for (int qt = 0; qt < 4; qt++){
      int q = qh*512 + wv*128 + pass*64 + qt*16 + col;
      #pragma unroll
      for (int ks = 0; ks < 4; ks++)
        Bf[qt][ks] = *(const bf16x8*)&W3BF[q*128 + ks*32 + kc*8];
    }
    float smx[4], smn[4], ssm[4], ssqv[4];
    #pragma unroll
    for (int qt = 0; qt < 4; qt++){ smx[qt] = -3.4e38f; smn[qt] = 3.4e38f; ssm[qt] = 0.f; ssqv[qt] = 0.f; }

    #pragma unroll 1
    for (int st = 0; st < 8; ++st){
      bf16x8 Af[4];
      int row = st*16 + col;
      #pragma unroll
      for (int ks = 0; ks < 4; ks++){
        int chunk = (ks*4 + kc) ^ (row & 7);
        Af[ks] = *(const bf16x8*)&As[row*128 + chunk*8];
      }
      #pragma unroll
      for (int qt = 0; qt < 4; qt++){
        f32x4 acc = {0.f, 0.f, 0.f, 0.f};
        #pragma unroll
        for (int ks = 0; ks < 4; ks++)
          acc = __builtin_amdgcn_mfma_f32_16x16x32_bf16(Af[ks], Bf[qt][ks], acc, 0, 0, 0);
        #pragma unroll
        for (int r = 0; r < 4; r++){
          float vv = acc[r];
          smx[qt] = fmaxf(smx[qt], vv); smn[qt] = fminf(smn[qt], vv);
          ssm[qt] += vv; ssqv[qt] += vv*vv;
        }
      }
    }
    #pragma unroll
    for (int qt = 0; qt < 4; qt++){
      #pragma unroll
      for (int off = 16; off <= 32; off <<= 1){
        smx[qt] = fmaxf(smx[qt], __shfl_xor(smx[qt], off));
        smn[qt] = fminf(smn[qt], __shfl_xor(smn[qt], off));
        ssm[qt] += __shfl_xor(ssm[qt], off);
        ssqv[qt] += __shfl_xor(ssqv[qt], off);
      }
    }
    if (kc == 0){
      #pragma unroll
      for (int qt = 0; qt < 4; qt++){
        int q = qh*512 + wv*128 + pass*64 + qt*16 + col;
        atomicMax(&P3MAX[b*1024 + q], fkey(smx[qt]));
        atomicMin(&P3MIN[b*1024 + q], fkey(smn[qt]));
        atomicAdd(&S3SUM[q], (double)ssm[qt]);
        atomicAdd(&S3SQ[q],  (double)ssqv[qt]);
      }
    }
  }
}

// ---------------- FC1: bn3+relu fused staging + dot (1024->512) ----------------
__global__ __launch_bounds__(256) void k_fc1(const double* __restrict__ S3SUM,
      const double* __restrict__ S3SQ, const unsigned* __restrict__ P3MAX,
      const unsigned* __restrict__ P3MIN, const float* __restrict__ g3,
      const float* __restrict__ b3, const float* __restrict__ Wf1,
      float* __restrict__ dots){
  __shared__ float Xs[16*64];
  const int tid = threadIdx.x;
  const int o = blockIdx.x*64 + (tid & 63);
  const int wvv = tid >> 6;
  const int c0 = blockIdx.y*64;
  for (int i = tid; i < 1024; i += 256){
    int bb = i >> 6, cc = i & 63;
    int q = c0 + cc;
    int id = bb*1024 + q;
    double mean = S3SUM[q] * (1.0/32768.0);
    double var  = S3SQ[q] * (1.0/32768.0) - mean*mean;
    double a = (double)g3[q] / sqrt(var + 1e-5);
    double cbn = (double)b3[q] - a*mean;
    float v = fdec((a >= 0.0) ? P3MAX[id] : P3MIN[id]);
    Xs[bb*64 + cc] = fmaxf((float)(a*(double)v + cbn), 0.f);
  }
  __syncthreads();
  float acc[16];
  #pragma unroll
  for (int bb = 0; bb < 16; bb++) acc[bb] = 0.f;
  for (int cc = wvv*16; cc < wvv*16 + 16; ++cc){
    float w = Wf1[(size_t)(c0+cc)*512 + o];
    #pragma unroll
    for (int bb = 0; bb < 16; bb++) acc[bb] += Xs[bb*64 + cc]*w;
  }
  #pragma unroll
  for (int bb = 0; bb < 16; bb++) atomicAdd(&dots[bb*512 + o], acc[bb]);
}

// ---------------- FC2: bn(f1) fused staging + dot (512->256) ----------------
__global__ __launch_bounds__(256) void k_fc2(const float* __restrict__ DOTS1,
      const float* __restrict__ gf1, const float* __restrict__ bf1,
      const float* __restrict__ Wf2, float* __restrict__ dots){
  __shared__ float Xs[16*32];
  const int tid = threadIdx.x;
  const int o = blockIdx.x*64 + (tid & 63);
  const int wvv = tid >> 6;
  const int c0 = blockIdx.y*32;
  if (tid < 32){
    int o1 = c0 + tid;
    float d[16]; float m = 0.f;
    #pragma unroll
    for (int bb = 0; bb < 16; bb++){ d[bb] = DOTS1[bb*512 + o1]; m += d[bb]; }
    m *= (1.f/16.f);
    float vv = 0.f;
    #pragma unroll
    for (int bb = 0; bb < 16; bb++){ float x = d[bb]-m; vv += x*x; }
    vv *= (1.f/16.f);
    float a = gf1[o1] * rsqrtf(vv + 1e-5f);
    #pragma unroll
    for (int bb = 0; bb < 16; bb++)
      Xs[bb*32 + tid] = fmaxf(a*(d[bb]-m) + bf1[o1], 0.f);
  }
  __syncthreads();
  float acc[16];
  #pragma unroll
  for (int bb = 0; bb < 16; bb++) acc[bb] = 0.f;
  for (int cc = wvv*8; cc < wvv*8 + 8; ++cc){
    float w = Wf2[(size_t)(c0+cc)*256 + o];
    #pragma unroll
    for (int bb = 0; bb < 16; bb++) acc[bb] += Xs[bb*32 + cc]*w;
  }
  #pragma unroll
  for (int bb = 0; bb < 16; bb++) atomicAdd(&dots[bb*256 + o], acc[bb]);
}

// ---------------- HEAD: bn(f2) fused + 256->9 + bias ----------------
__global__ __launch_bounds__(256) void k_head(const float* __restrict__ DOTS2,
      const float* __restrict__ gf2, const float* __restrict__ bf2,
      const float* __restrict__ Wf3, const float* __restrict__ bf3,
      float* __restrict__ out){
  __shared__ float R5s[16*256];        // 16 KB
  const int tid = threadIdx.x;
  {
    int o = tid;
    float d[16]; float m = 0.f;
    #pragma unroll
    for (int bb = 0; bb < 16; bb++){ d[bb] = DOTS2[bb*256 + o]; m += d[bb]; }
    m *= (1.f/16.f);
    float vv = 0.f;
    #pragma unroll
    for (int bb = 0; bb < 16; bb++){ float x = d[bb]-m; vv += x*x; }
    vv *= (1.f/16.f);
    float a = gf2[o] * rsqrtf(vv + 1e-5f);
    #pragma unroll
    for (int bb = 0; bb < 16; bb++)
      R5s[bb*256 + o] = fmaxf(a*(d[bb]-m) + bf2[o], 0.f);
  }
  __syncthreads();
  if (tid < 144){
    int b = tid/9, j = tid - b*9;
    float acc = bf3[j];
    for (int cq = 0; cq < 256; cq++) acc += R5s[b*256 + cq]*Wf3[cq*9 + j];
    out[tid] = acc;
  }
}

extern "C" void kernel_launch(void* const* d_in, const int* in_sizes, int n_in,
                              void* d_out, int out_size, void* d_ws, size_t ws_size,
                              hipStream_t stream) {
  if (ws_size < WS_NEEDED) return;
  const float* pc  = (const float*)d_in[0];
  const float* W1  = (const float*)d_in[1];
  const float* g1  = (const float*)d_in[2];
  const float* b1  = (const float*)d_in[3];
  const float* W2  = (const float*)d_in[4];
  const float* g2  = (const float*)d_in[5];
  const float* b2  = (const float*)d_in[6];
  const float* W3  = (const float*)d_in[7];
  const float* g3  = (const float*)d_in[8];
  const float* b3  = (const float*)d_in[9];
  const float* Wf1 = (const float*)d_in[10];
  const float* gf1 = (const float*)d_in[11];
  const float* bf1 = (const float*)d_in[12];
  const float* Wf2 = (const float*)d_in[13];
  const float* gf2 = (const float*)d_in[14];
  const float* bf2 = (const float*)d_in[15];
  const float* Wf3 = (const float*)d_in[16];
  const float* bf3 = (const float*)d_in[17];

  char* ws = (char*)d_ws;
  int*      IDX   = (int*)     (ws + OFF_IDX);
  short*    P2MAXp= (short*)   (ws + OFF_P2MAX);
  short*    P2MINp= (short*)   (ws + OFF_P2MIN);
  float*    PS2p  = (float*)   (ws + OFF_PS2);
  float*    PQ2p  = (float*)   (ws + OFF_PQ2);
  double*   MOMp  = (double*)  (ws + OFF_MOM);
  float*    A2C2p = (float*)   (ws + OFF_A2C2);
  double*   S3SUMp= (double*)  (ws + OFF_S3SUM);
  double*   S3SQp = (double*)  (ws + OFF_S3SQ);
  unsigned* P3MAXp= (unsigned*)(ws + OFF_P3MAX);
  unsigned* P3MINp= (unsigned*)(ws + OFF_P3MIN);
  float*    DOTS1p= (float*)   (ws + OFF_DOTS1);
  float*    DOTS2p= (float*)   (ws + OFF_DOTS2);
  short*    W2BFp = (short*)   (ws + OFF_W2BF);
  short*    W3BFp = (short*)   (ws + OFF_W3BF);

  k_setup <<<dim3(68),      256, 0, stream>>>(ws, W2, W3, W2BFp, W3BFp);
  k_knn   <<<dim3(64,16),   512, 0, stream>>>(pc, IDX, MOMp);
  k_conv12<<<dim3(128,16),  256, 0, stream>>>(pc, IDX, MOMp, W1, g1, b1, W2BFp, PS2p, PQ2p, P2MAXp, P2MINp);
  k_coef2 <<<dim3(128),     256, 0, stream>>>(PS2p, PQ2p, g2, b2, A2C2p);
  k_conv3 <<<dim3(16,16,2), 256, 0, stream>>>(P2MAXp, P2MINp, A2C2p, W3BFp, S3SUMp, S3SQp, P3MAXp, P3MINp);
  k_fc1   <<<dim3(8,16),    256, 0, stream>>>(S3SUMp, S3SQp, P3MAXp, P3MINp, g3, b3, Wf1, DOTS1p);
  k_fc2   <<<dim3(4,16),    256, 0, stream>>>(DOTS1p, gf1, bf1, Wf2, DOTS2p);
  k_head  <<<dim3(1),       256, 0, stream>>>(DOTS2p, gf2, bf2, Wf3, bf3, (float*)d_out);
}

// Round 11
// 195.131 us; speedup vs baseline: 1.0713x; 1.0713x over previous
//
#include <hip/hip_runtime.h>
#include <math.h>

#define Nn 2048

// ---------------- workspace layout (bytes) ----------------
#define OFF_IDX    ((size_t)0)                    // 16*2048*20*4 = 2.62 MB
#define OFF_P2MAX  (((size_t)4)  << 20)           // 16*2048*128*2 = 8.39 MB (bf16)
#define OFF_P2MIN  (((size_t)13) << 20)           // 8.39 MB (bf16)
#define OFF_PS2    (((size_t)22) << 20)           // 128*2048 float = 1 MB
#define OFF_PQ2    (((size_t)23) << 20)           // 1 MB
#define OFF_STATS  (((size_t)24) << 20)
#define OFF_MOM    (OFF_STATS + 0)                // 27 double
#define OFF_A2C2   (OFF_STATS + 8192)             // 256 float
#define OFF_S3SUM  (OFF_STATS + 12288)            // 1024 double
#define OFF_S3SQ   (OFF_STATS + 20480)            // 1024 double
#define OFF_P3MAX  (OFF_STATS + 28672)            // 16*1024 uint
#define OFF_P3MIN  (OFF_STATS + 94208)            // 16*1024 uint
#define OFF_DOTS1  (OFF_STATS + 274432)           // 16*512 float
#define OFF_DOTS2  (OFF_STATS + 307200)           // 16*256 float
#define OFF_W2BF   (OFF_STATS + 323584)           // 128*64 bf16 (q-major)
#define OFF_W3BF   (OFF_STATS + 339968)           // 1024*128 bf16 (q-major)
#define WS_NEEDED  (OFF_STATS + 602112)

typedef __attribute__((ext_vector_type(8))) short bf16x8;
typedef __attribute__((ext_vector_type(4))) float f32x4;

__device__ __forceinline__ unsigned fkey(float f){
  unsigned u = __float_as_uint(f);
  return u ^ ((unsigned)((int)u >> 31) | 0x80000000u);   // monotone float->uint
}
__device__ __forceinline__ float fdec(unsigned k){
  unsigned u = (k & 0x80000000u) ? (k & 0x7FFFFFFFu) : ~k;
  return __uint_as_float(u);
}
__device__ __forceinline__ short f2bf(float x){
  unsigned u = __float_as_uint(x);
  u += 0x7fffu + ((u >> 16) & 1u);                // RNE
  return (short)(u >> 16);
}
__device__ __forceinline__ float bf2f(short v){
  return __uint_as_float(((unsigned)(unsigned short)v) << 16);
}
__device__ __forceinline__ unsigned med3u(unsigned a, unsigned b, unsigned c){
  unsigned d;
  asm("v_med3_u32 %0, %1, %2, %3" : "=v"(d) : "v"(a), "v"(b), "v"(c));
  return d;
}
// branch-free insert of x into ascending sorted top-20 (uint keys)
__device__ __forceinline__ void insert20u(unsigned (&m)[20], unsigned x){
  #pragma unroll
  for (int t = 0; t < 19; t++) m[t] = med3u(m[t], m[t+1], x);
  m[19] = (x > m[19]) ? x : m[19];
}

// ---------------- K0: init accumulators + bf16 weight pre-cast ----------------
__global__ __launch_bounds__(256) void k_setup(char* __restrict__ ws,
      const float* __restrict__ W2, const float* __restrict__ W3,
      short* __restrict__ W2BF, short* __restrict__ W3BF){
  int i = blockIdx.x*256 + threadIdx.x;
  if (i < 7168) ((unsigned*)(ws + OFF_MOM))[i] = 0u;       // MOM..S3SQ
  if (i < 16384){
    ((unsigned*)(ws + OFF_P3MAX))[i] = 0u;
    ((unsigned*)(ws + OFF_P3MIN))[i] = 0xFFFFFFFFu;
  }
  if (i < 12288) ((float*)(ws + OFF_DOTS1))[i] = 0.f;      // DOTS1+DOTS2
  if (i < 16384){                      // W3: (q, k-chunk of 8)
    int q = i >> 4, k0 = (i & 15)*8;
    bf16x8 vv;
    #pragma unroll
    for (int j = 0; j < 8; j++) vv[j] = f2bf(W3[(size_t)(k0+j)*1024 + q]);
    *(bf16x8*)&W3BF[q*128 + k0] = vv;
  } else if (i < 17408){               // W2: (q, k-chunk of 8)
    int id2 = i - 16384;
    int q = id2 >> 3, k0 = (id2 & 7)*8;
    bf16x8 vv;
    #pragma unroll
    for (int j = 0; j < 8; j++) vv[j] = f2bf(W2[(k0+j)*128 + q]);
    *(bf16x8*)&W2BF[q*64 + k0] = vv;
  }
}

// ---------------- K1: KNN top-20 via index-packed uint keys ----------------
// grid (32,16), block 512. 8 lanes/query x 256 candidates (measured optimum:
// total work = scan 2048*26 + L*log2(L)*420; L=8 minimizes it at full issue
// efficiency — L=16 was +27% total work, r10). Key: nd' = Q.P - 0.5|P|^2
// (order-equivalent); pk = (fkey(nd') & ~0x7FF) | (2047-m) packs the index
// in the low 11 bits (ties -> lowest index). One scan, register-only 3-stage
// butterfly merge, indices decoded straight from registers.
__global__ __launch_bounds__(512) void k_knn(const float* __restrict__ pc,
                                             int* __restrict__ idxg,
                                             double* __restrict__ MOM){
  __shared__ float4 pts[Nn];           // 32 KB; w = -0.5*|P|^2
  __shared__ float momS[27];
  const int tid = threadIdx.x;
  const int b = blockIdx.y;
  const int n0 = blockIdx.x*64;
  const float* pcb = pc + b*3*Nn;
  for (int i = tid; i < Nn; i += 512){
    float x = pcb[i], y = pcb[Nn+i], z = pcb[2*Nn+i];
    pts[i] = make_float4(x, y, z, -0.5f*(x*x + y*y + z*z));
  }
  if (tid < 27) momS[tid] = 0.f;
  __syncthreads();

  const int ql = tid >> 3, c = tid & 7;
  const int n = n0 + ql;
  const float4 Q = pts[n];

  unsigned v[20];
  #pragma unroll
  for (int t = 0; t < 20; t++) v[t] = 0u;
  #pragma unroll 1
  for (int i = 0; i < 256; i += 4){
    int m0 = (i+0)*8 + c, m1 = (i+1)*8 + c, m2 = (i+2)*8 + c, m3 = (i+3)*8 + c;
    float4 P0 = pts[m0];
    float4 P1 = pts[m1];
    float4 P2 = pts[m2];
    float4 P3 = pts[m3];
    float nd0 = fmaf(Q.x, P0.x, fmaf(Q.y, P0.y, fmaf(Q.z, P0.z, P0.w)));
    float nd1 = fmaf(Q.x, P1.x, fmaf(Q.y, P1.y, fmaf(Q.z, P1.z, P1.w)));
    float nd2 = fmaf(Q.x, P2.x, fmaf(Q.y, P2.y, fmaf(Q.z, P2.z, P2.w)));
    float nd3 = fmaf(Q.x, P3.x, fmaf(Q.y, P3.y, fmaf(Q.z, P3.z, P3.w)));
    insert20u(v, (fkey(nd0) & 0xFFFFF800u) | (unsigned)(2047 - m0));
    insert20u(v, (fkey(nd1) & 0xFFFFF800u) | (unsigned)(2047 - m1));
    insert20u(v, (fkey(nd2) & 0xFFFFF800u) | (unsigned)(2047 - m2));
    insert20u(v, (fkey(nd3) & 0xFFFFF800u) | (unsigned)(2047 - m3));
  }

  // butterfly merge across the 8 lanes of this query (top-20-of-union is
  // associative, commutative, idempotent -> hypercube allreduce is exact)
  #pragma unroll
  for (int stage = 4; stage >= 1; stage >>= 1){
    unsigned w[20];
    #pragma unroll
    for (int t = 0; t < 20; t++) w[t] = (unsigned)__shfl_xor((int)v[t], stage);
    #pragma unroll
    for (int t = 0; t < 20; t++) insert20u(v, w[t]);
  }

  // decode + write indices; accumulate moments from this lane's slots
  int* myidx = &idxg[((size_t)((b<<11) + n))*20];
  float s1[6] = {0,0,0,0,0,0};
  float s2[21] = {0,0,0,0,0,0,0,0,0,0,0,0,0,0,0,0,0,0,0,0,0};
  #pragma unroll
  for (int t = 0; t < 3; t++){
    int slot = c + t*8;
    if (slot < 20){
      int m = 2047 - (int)(v[slot] & 0x7FFu);
      myidx[slot] = m;
      float4 P = pts[m];
      float e[6] = {Q.x, Q.y, Q.z, P.x - Q.x, P.y - Q.y, P.z - Q.z};
      int u = 0;
      #pragma unroll
      for (int a = 0; a < 6; a++){
        s1[a] += e[a];
        #pragma unroll
        for (int bq = a; bq < 6; bq++){ s2[u] += e[a]*e[bq]; u++; }
      }
    }
  }
  #pragma unroll
  for (int a = 0; a < 6; a++)
    for (int off = 32; off > 0; off >>= 1) s1[a] += __shfl_xor(s1[a], off);
  #pragma unroll
  for (int u = 0; u < 21; u++)
    for (int off = 32; off > 0; off >>= 1) s2[u] += __shfl_xor(s2[u], off);
  if ((tid & 63) == 0){
    #pragma unroll
    for (int a = 0; a < 6; a++) atomicAdd(&momS[a], s1[a]);
    #pragma unroll
    for (int u = 0; u < 21; u++) atomicAdd(&momS[6+u], s2[u]);
  }
  __syncthreads();
  if (tid < 27) atomicAdd(&MOM[tid], (double)momS[tid]);
}

// ---------------- K4: conv1+bn1+relu+conv2 via MFMA; coef1 folded in ----------------
__global__ __launch_bounds__(256) void k_conv12(const float* __restrict__ pc,
      const int* __restrict__ idxg, const double* __restrict__ MOM,
      const float* __restrict__ W1, const float* __restrict__ g1,
      const float* __restrict__ b1, const short* __restrict__ W2BF,
      float* __restrict__ PS2, float* __restrict__ PQ2,
      short* __restrict__ P2MAX, short* __restrict__ P2MIN){
  __shared__ float es[6][512];         // 12 KB
  __shared__ short h1s[256*64];        // 32 KB (reused for both chunks)
  __shared__ float w1s[448];
  __shared__ float ssum[128], ssq[128];
  const int tid = threadIdx.x;
  const int b = blockIdx.y;
  const int n0 = blockIdx.x*16;
  const float* pcb = pc + b*3*Nn;

  if (tid < 64){
    const int o = tid;
    const double inv = 1.0/655360.0;
    double w[6]; double m = 0.0;
    #pragma unroll
    for (int cc = 0; cc < 6; cc++){ w[cc] = (double)W1[cc*64+o]; m += w[cc]*MOM[cc]*inv; }
    double e2 = 0.0; int u = 0;
    #pragma unroll
    for (int cc = 0; cc < 6; cc++){
      #pragma unroll
      for (int cp = cc; cp < 6; cp++){
        double mm = MOM[6+u]*inv; u++;
        e2 += (cc == cp) ? w[cc]*w[cc]*mm : 2.0*w[cc]*w[cp]*mm;
      }
    }
    double var = e2 - m*m;
    double a = (double)g1[o] / sqrt(var + 1e-5);
    #pragma unroll
    for (int cc = 0; cc < 6; cc++) w1s[cc*64+o] = (float)(a*w[cc]);
    w1s[384+o] = (float)((double)b1[o] - a*m);
  }

  for (int s = tid; s < 512; s += 256){
    int nl = s >> 5, kk = s & 31;
    int n = n0 + nl;
    int kke = (kk < 20) ? kk : 0;
    int m = idxg[((size_t)((b<<11)+n))*20 + kke] & 2047;
    float cx = pcb[n],  cy = pcb[Nn+n],  cz = pcb[2*Nn+n];
    float px = pcb[m],  py = pcb[Nn+m],  pz = pcb[2*Nn+m];
    es[0][s] = cx;    es[1][s] = cy;    es[2][s] = cz;
    es[3][s] = px-cx; es[4][s] = py-cy; es[5][s] = pz-cz;
  }
  __syncthreads();

  const int l = tid & 63, wv = tid >> 6;
  const int col = l & 15, kc = l >> 4;

  bf16x8 Bf[2][2];
  #pragma unroll
  for (int qt = 0; qt < 2; qt++){
    int q = wv*32 + qt*16 + col;
    #pragma unroll
    for (int ks = 0; ks < 2; ks++)
      Bf[qt][ks] = *(const bf16x8*)&W2BF[q*64 + ks*32 + kc*8];
  }

  float smacc[2] = {0.f, 0.f}, sqacc[2] = {0.f, 0.f};
  const bool t1real = (kc == 0);

  #pragma unroll 1
  for (int ch = 0; ch < 2; ch++){
    for (int i = tid; i < 2048; i += 256){
      int sl = i >> 3, oc = i & 7;
      int s = (ch << 8) + sl;
      bf16x8 hv;
      #pragma unroll
      for (int j = 0; j < 8; j++){
        int o = oc*8 + j;
        float acc = w1s[384 + o];
        #pragma unroll
        for (int cc = 0; cc < 6; cc++) acc = fmaf(w1s[cc*64 + o], es[cc][s], acc);
        hv[j] = f2bf(fmaxf(acc, 0.f));
      }
      *(bf16x8*)&h1s[sl*64 + ((oc ^ (sl & 7)) << 3)] = hv;
    }
    __syncthreads();

    #pragma unroll 1
    for (int g2 = 0; g2 < 8; g2++){
      const int g = ch*8 + g2;
      bf16x8 Af[2][2];
      #pragma unroll
      for (int t = 0; t < 2; t++){
        int rl = g2*32 + t*16 + col;
        #pragma unroll
        for (int ks = 0; ks < 2; ks++){
          int chunk = (ks*4 + kc) ^ (rl & 7);
          Af[t][ks] = *(const bf16x8*)&h1s[rl*64 + chunk*8];
        }
      }
      #pragma unroll
      for (int qt = 0; qt < 2; qt++){
        f32x4 a0 = {0.f,0.f,0.f,0.f}, a1 = {0.f,0.f,0.f,0.f};
        a0 = __builtin_amdgcn_mfma_f32_16x16x32_bf16(Af[0][0], Bf[qt][0], a0, 0,0,0);
        a0 = __builtin_amdgcn_mfma_f32_16x16x32_bf16(Af[0][1], Bf[qt][1], a0, 0,0,0);
        a1 = __builtin_amdgcn_mfma_f32_16x16x32_bf16(Af[1][0], Bf[qt][0], a1, 0,0,0);
        a1 = __builtin_amdgcn_mfma_f32_16x16x32_bf16(Af[1][1], Bf[qt][1], a1, 0,0,0);
        float mx = a0[0], mn = a0[0], sm = 0.f, sq = 0.f;
        #pragma unroll
        for (int r = 0; r < 4; r++){
          float v0 = a0[r], v1 = a1[r];
          mx = fmaxf(mx, fmaxf(v0, v1));
          mn = fminf(mn, fminf(v0, v1));
          sm += v0; sq += v0*v0;
        }
        if (t1real){
          #pragma unroll
          for (int r = 0; r < 4; r++){ float v1 = a1[r]; sm += v1; sq += v1*v1; }
        }
        smacc[qt] += sm; sqacc[qt] += sq;
        mx = fmaxf(mx, __shfl_xor(mx, 16)); mx = fmaxf(mx, __shfl_xor(mx, 32));
        mn = fminf(mn, __shfl_xor(mn, 16)); mn = fminf(mn, __shfl_xor(mn, 32));
        if (kc == 0){
          size_t base = ((size_t)(b*Nn + n0 + g))*128 + (size_t)(wv*32 + qt*16 + col);
          P2MAX[base] = f2bf(mx);
          P2MIN[base] = f2bf(mn);
        }
      }
    }
    __syncthreads();
  }

  #pragma unroll
  for (int qt = 0; qt < 2; qt++){
    smacc[qt] += __shfl_xor(smacc[qt], 16); smacc[qt] += __shfl_xor(smacc[qt], 32);
    sqacc[qt] += __shfl_xor(sqacc[qt], 16); sqacc[qt] += __shfl_xor(sqacc[qt], 32);
    if (kc == 0){
      ssum[wv*32 + qt*16 + col] = smacc[qt];
      ssq [wv*32 + qt*16 + col] = sqacc[qt];
    }
  }
  __syncthreads();
  if (tid < 128){
    int bid = b*128 + blockIdx.x;
    PS2[tid*2048 + bid] = ssum[tid];
    PQ2[tid*2048 + bid] = ssq[tid];
  }
}

// ---------------- K5: bn2 affine from partial buffers ----------------
__global__ __launch_bounds__(256) void k_coef2(const float* __restrict__ PS2,
        const float* __restrict__ PQ2, const float* __restrict__ g2,
        const float* __restrict__ b2, float* __restrict__ A2C2){
  __shared__ float sred[4], qred[4];
  const int p = blockIdx.x;
  const int tid = threadIdx.x;
  float s = 0.f, q = 0.f;
  for (int i = tid; i < 2048; i += 256){ s += PS2[p*2048 + i]; q += PQ2[p*2048 + i]; }
  #pragma unroll
  for (int off = 32; off > 0; off >>= 1){ s += __shfl_xor(s, off); q += __shfl_xor(q, off); }
  if ((tid & 63) == 0){ sred[tid >> 6] = s; qred[tid >> 6] = q; }
  __syncthreads();
  if (tid == 0){
    double sum = (double)sred[0] + sred[1] + sred[2] + sred[3];
    double sq  = (double)qred[0] + qred[1] + qred[2] + qred[3];
    double mean = sum * (1.0/655360.0);
    double var  = sq  * (1.0/655360.0) - mean*mean;
    double a = (double)g2[p] / sqrt(var + 1e-5);
    A2C2[p]     = (float)a;
    A2C2[128+p] = (float)((double)b2[p] - a*mean);
  }
}

// ---------------- K6: bn2+relu + conv3 via MFMA; bn3 stats + n-pool ----------------
__global__ __launch_bounds__(256) void k_conv3(const short* __restrict__ P2MAX,
      const short* __restrict__ P2MIN, const float* __restrict__ A2C2,
      const short* __restrict__ W3BF, double* __restrict__ S3SUM,
      double* __restrict__ S3SQ, unsigned* __restrict__ P3MAX,
      unsigned* __restrict__ P3MIN){
  __shared__ short As[128*128];
  __shared__ float a2[128], c2[128];
  const int tid = threadIdx.x;
  const int b = blockIdx.y;
  const int n0 = blockIdx.x*128;
  const int qh = blockIdx.z;
  if (tid < 128){ a2[tid] = A2C2[tid]; c2[tid] = A2C2[128+tid]; }
  __syncthreads();

  for (int idx = tid; idx < 2048; idx += 256){
    int s = idx >> 4, oc = idx & 15;
    size_t base = ((size_t)(b*Nn + n0 + s))*128 + (size_t)(oc*8);
    bf16x8 vmx = *(const bf16x8*)&P2MAX[base];
    bf16x8 vmn = *(const bf16x8*)&P2MIN[base];
    bf16x8 vv;
    #pragma unroll
    for (int j = 0; j < 8; j++){
      int o = oc*8 + j;
      float aa = a2[o];
      float vsel = bf2f((aa >= 0.f) ? vmx[j] : vmn[j]);
      vv[j] = f2bf(fmaxf(aa*vsel + c2[o], 0.f));
    }
    int chunk = oc ^ (s & 7);
    *(bf16x8*)&As[s*128 + chunk*8] = vv;
  }
  __syncthreads();

  const int l = tid & 63, wv = tid >> 6;
  const int col = l & 15, kc = l >> 4;

  #pragma unroll 1
  for (int pass = 0; pass < 2; ++pass){
    bf16x8 Bf[4][4];
    #pragma unroll
    for (int qt = 0; qt < 4; qt++){
      int q = qh*512 + wv*128 + pass*64 + qt*16 + col;
      #pragma unroll
      for (int ks = 0; ks < 4; ks++)
        Bf[qt][ks] = *(const bf16x8*)&W3BF[q*128 + ks*32 + kc*8];
    }
    float smx[4], smn[4], ssm[4], ssqv[4];
    #pragma unroll
    for (int qt = 0; qt < 4; qt++){ smx[qt] = -3.4e38f; smn[qt] = 3.4e38f; ssm[qt] = 0.f; ssqv[qt] = 0.f; }

    #pragma unroll 1
    for (int st = 0; st < 8; ++st){
      bf16x8 Af[4];
      int row = st*16 + col;
      #pragma unroll
      for (int ks = 0; ks < 4; ks++){
        int chunk = (ks*4 + kc) ^ (row & 7);
        Af[ks] = *(const bf16x8*)&As[row*128 + chunk*8];
      }
      #pragma unroll
      for (int qt = 0; qt < 4; qt++){
        f32x4 acc = {0.f, 0.f, 0.f, 0.f};
        #pragma unroll
        for (int ks = 0; ks < 4; ks++)
          acc = __builtin_amdgcn_mfma_f32_16x16x32_bf16(Af[ks], Bf[qt][ks], acc, 0, 0, 0);
        #pragma unroll
        for (int r = 0; r < 4; r++){
          float vv = acc[r];
          smx[qt] = fmaxf(smx[qt], vv); smn[qt] = fminf(smn[qt], vv);
          ssm[qt] += vv; ssqv[qt] += vv*vv;
        }
      }
    }
    #pragma unroll
    for (int qt = 0; qt < 4; qt++){
      #pragma unroll
      for (int off = 16; off <= 32; off <<= 1){
        smx[qt] = fmaxf(smx[qt], __shfl_xor(smx[qt], off));
        smn[qt] = fminf(smn[qt], __shfl_xor(smn[qt], off));
        ssm[qt] += __shfl_xor(ssm[qt], off);
        ssqv[qt] += __shfl_xor(ssqv[qt], off);
      }
    }
    if (kc == 0){
      #pragma unroll
      for (int qt = 0; qt < 4; qt++){
        int q = qh*512 + wv*128 + pass*64 + qt*16 + col;
        atomicMax(&P3MAX[b*1024 + q], fkey(smx[qt]));
        atomicMin(&P3MIN[b*1024 + q], fkey(smn[qt]));
        atomicAdd(&S3SUM[q], (double)ssm[qt]);
        atomicAdd(&S3SQ[q],  (double)ssqv[qt]);
      }
    }
  }
}

// ---------------- FC1: bn3+relu fused staging + dot (1024->512) ----------------
__global__ __launch_bounds__(256) void k_fc1(const double* __restrict__ S3SUM,
      const double* __restrict__ S3SQ, const unsigned* __restrict__ P3MAX,
      const unsigned* __restrict__ P3MIN, const float* __restrict__ g3,
      const float* __restrict__ b3, const float* __restrict__ Wf1,
      float* __restrict__ dots){
  __shared__ float Xs[16*64];
  const int tid = threadIdx.x;
  const int o = blockIdx.x*64 + (tid & 63);
  const int wvv = tid >> 6;
  const int c0 = blockIdx.y*64;
  for (int i = tid; i < 1024; i += 256){
    int bb = i >> 6, cc = i & 63;
    int q = c0 + cc;
    int id = bb*1024 + q;
    double mean = S3SUM[q] * (1.0/32768.0);
    double var  = S3SQ[q] * (1.0/32768.0) - mean*mean;
    double a = (double)g3[q] / sqrt(var + 1e-5);
    double cbn = (double)b3[q] - a*mean;
    float v = fdec((a >= 0.0) ? P3MAX[id] : P3MIN[id]);
    Xs[bb*64 + cc] = fmaxf((float)(a*(double)v + cbn), 0.f);
  }
  __syncthreads();
  float acc[16];
  #pragma unroll
  for (int bb = 0; bb < 16; bb++) acc[bb] = 0.f;
  for (int cc = wvv*16; cc < wvv*16 + 16; ++cc){
    float w = Wf1[(size_t)(c0+cc)*512 + o];
    #pragma unroll
    for (int bb = 0; bb < 16; bb++) acc[bb] += Xs[bb*64 + cc]*w;
  }
  #pragma unroll
  for (int bb = 0; bb < 16; bb++) atomicAdd(&dots[bb*512 + o], acc[bb]);
}

// ---------------- FC2: bn(f1) fused staging + dot (512->256) ----------------
__global__ __launch_bounds__(256) void k_fc2(const float* __restrict__ DOTS1,
      const float* __restrict__ gf1, const float* __restrict__ bf1,
      const float* __restrict__ Wf2, float* __restrict__ dots){
  __shared__ float Xs[16*32];
  const int tid = threadIdx.x;
  const int o = blockIdx.x*64 + (tid & 63);
  const int wvv = tid >> 6;
  const int c0 = blockIdx.y*32;
  if (tid < 32){
    int o1 = c0 + tid;
    float d[16]; float m = 0.f;
    #pragma unroll
    for (int bb = 0; bb < 16; bb++){ d[bb] = DOTS1[bb*512 + o1]; m += d[bb]; }
    m *= (1.f/16.f);
    float vv = 0.f;
    #pragma unroll
    for (int bb = 0; bb < 16; bb++){ float x = d[bb]-m; vv += x*x; }
    vv *= (1.f/16.f);
    float a = gf1[o1] * rsqrtf(vv + 1e-5f);
    #pragma unroll
    for (int bb = 0; bb < 16; bb++)
      Xs[bb*32 + tid] = fmaxf(a*(d[bb]-m) + bf1[o1], 0.f);
  }
  __syncthreads();
  float acc[16];
  #pragma unroll
  for (int bb = 0; bb < 16; bb++) acc[bb] = 0.f;
  for (int cc = wvv*8; cc < wvv*8 + 8; ++cc){
    float w = Wf2[(size_t)(c0+cc)*256 + o];
    #pragma unroll
    for (int bb = 0; bb < 16; bb++) acc[bb] += Xs[bb*32 + cc]*w;
  }
  #pragma unroll
  for (int bb = 0; bb < 16; bb++) atomicAdd(&dots[bb*256 + o], acc[bb]);
}

// ---------------- HEAD: bn(f2) fused + 256->9 + bias ----------------
__global__ __launch_bounds__(256) void k_head(const float* __restrict__ DOTS2,
      const float* __restrict__ gf2, const float* __restrict__ bf2,
      const float* __restrict__ Wf3, const float* __restrict__ bf3,
      float* __restrict__ out){
  __shared__ float R5s[16*256];        // 16 KB
  const int tid = threadIdx.x;
  {
    int o = tid;
    float d[16]; float m = 0.f;
    #pragma unroll
    for (int bb = 0; bb < 16; bb++){ d[bb] = DOTS2[bb*256 + o]; m += d[bb]; }
    m *= (1.f/16.f);
    float vv = 0.f;
    #pragma unroll
    for (int bb = 0; bb < 16; bb++){ float x = d[bb]-m; vv += x*x; }
    vv *= (1.f/16.f);
    float a = gf2[o] * rsqrtf(vv + 1e-5f);
    #pragma unroll
    for (int bb = 0; bb < 16; bb++)
      R5s[bb*256 + o] = fmaxf(a*(d[bb]-m) + bf2[o], 0.f);
  }
  __syncthreads();
  if (tid < 144){
    int b = tid/9, j = tid - b*9;
    float acc = bf3[j];
    for (int cq = 0; cq < 256; cq++) acc += R5s[b*256 + cq]*Wf3[cq*9 + j];
    out[tid] = acc;
  }
}

extern "C" void kernel_launch(void* const* d_in, const int* in_sizes, int n_in,
                              void* d_out, int out_size, void* d_ws, size_t ws_size,
                              hipStream_t stream) {
  if (ws_size < WS_NEEDED) return;
  const float* pc  = (const float*)d_in[0];
  const float* W1  = (const float*)d_in[1];
  const float* g1  = (const float*)d_in[2];
  const float* b1  = (const float*)d_in[3];
  const float* W2  = (const float*)d_in[4];
  const float* g2  = (const float*)d_in[5];
  const float* b2  = (const float*)d_in[6];
  const float* W3  = (const float*)d_in[7];
  const float* g3  = (const float*)d_in[8];
  const float* b3  = (const float*)d_in[9];
  const float* Wf1 = (const float*)d_in[10];
  const float* gf1 = (const float*)d_in[11];
  const float* bf1 = (const float*)d_in[12];
  const float* Wf2 = (const float*)d_in[13];
  const float* gf2 = (const float*)d_in[14];
  const float* bf2 = (const float*)d_in[15];
  const float* Wf3 = (const float*)d_in[16];
  const float* bf3 = (const float*)d_in[17];

  char* ws = (char*)d_ws;
  int*      IDX   = (int*)     (ws + OFF_IDX);
  short*    P2MAXp= (short*)   (ws + OFF_P2MAX);
  short*    P2MINp= (short*)   (ws + OFF_P2MIN);
  float*    PS2p  = (float*)   (ws + OFF_PS2);
  float*    PQ2p  = (float*)   (ws + OFF_PQ2);
  double*   MOMp  = (double*)  (ws + OFF_MOM);
  float*    A2C2p = (float*)   (ws + OFF_A2C2);
  double*   S3SUMp= (double*)  (ws + OFF_S3SUM);
  double*   S3SQp = (double*)  (ws + OFF_S3SQ);
  unsigned* P3MAXp= (unsigned*)(ws + OFF_P3MAX);
  unsigned* P3MINp= (unsigned*)(ws + OFF_P3MIN);
  float*    DOTS1p= (float*)   (ws + OFF_DOTS1);
  float*    DOTS2p= (float*)   (ws + OFF_DOTS2);
  short*    W2BFp = (short*)   (ws + OFF_W2BF);
  short*    W3BFp = (short*)   (ws + OFF_W3BF);

  k_setup <<<dim3(68),      256, 0, stream>>>(ws, W2, W3, W2BFp, W3BFp);
  k_knn   <<<dim3(32,16),   512, 0, stream>>>(pc, IDX, MOMp);
  k_conv12<<<dim3(128,16),  256, 0, stream>>>(pc, IDX, MOMp, W1, g1, b1, W2BFp, PS2p, PQ2p, P2MAXp, P2MINp);
  k_coef2 <<<dim3(128),     256, 0, stream>>>(PS2p, PQ2p, g2, b2, A2C2p);
  k_conv3 <<<dim3(16,16,2), 256, 0, stream>>>(P2MAXp, P2MINp, A2C2p, W3BFp, S3SUMp, S3SQp, P3MAXp, P3MINp);
  k_fc1   <<<dim3(8,16),    256, 0, stream>>>(S3SUMp, S3SQp, P3MAXp, P3MINp, g3, b3, Wf1, DOTS1p);
  k_fc2   <<<dim3(4,16),    256, 0, stream>>>(DOTS1p, gf1, bf1, Wf2, DOTS2p);
  k_head  <<<dim3(1),       256, 0, stream>>>(DOTS2p, gf2, bf2, Wf3, bf3, (float*)d_out);
}